// Round 1
// 409.606 us; speedup vs baseline: 1.0423x; 1.0423x over previous
//
#include <hip/hip_runtime.h>
#include <hip/hip_bf16.h>

#define N_NODES 100000
#define N_EDGES 1600000
#define NEG_SLOPE 0.2f
#define LN_EPS 1e-5f

// ---------------- GEMM: h = x @ W  (fp32, 128x128 tile, 8x8/thread) ----------------
// Fused epilogue: a_src[n][head] = dot(h[n, head*16 : head*16+16], att_src[head])
// computed from the accumulator registers (saves re-reading all of h).
__global__ __launch_bounds__(256) void gemm_kernel(const float* __restrict__ x,
                                                   const float* __restrict__ W,
                                                   const float* __restrict__ att_src,
                                                   float* __restrict__ h,
                                                   float* __restrict__ a_srcp) {
    __shared__ float xs[128 * 64];   // [r][k]  32 KB
    __shared__ float ws[64 * 128];   // [k][c]  32 KB
    const int t = threadIdx.x;
    const int nbase = blockIdx.x * 128;
    const int cx = (t & 15) * 8;     // 8 consecutive output cols
    const int ry = (t >> 4) * 8;     // 8 consecutive output rows
    float acc[8][8] = {};
    for (int kb = 0; kb < 2; ++kb) {
        __syncthreads();
        // stage x half-tile: 2048 float4s
        for (int i = t; i < 2048; i += 256) {
            int r = i >> 4, kq = i & 15;
            int gr = nbase + r;
            gr = gr < N_NODES ? gr : N_NODES - 1;
            *reinterpret_cast<float4*>(&xs[r * 64 + kq * 4]) =
                *reinterpret_cast<const float4*>(&x[(size_t)gr * 128 + kb * 64 + kq * 4]);
        }
        // stage W half-tile
        for (int i = t; i < 2048; i += 256) {
            int k = i >> 5, cq = i & 31;
            *reinterpret_cast<float4*>(&ws[k * 128 + cq * 4]) =
                *reinterpret_cast<const float4*>(&W[(size_t)(kb * 64 + k) * 128 + cq * 4]);
        }
        __syncthreads();
        for (int kq = 0; kq < 16; ++kq) {
            float4 xv[8];
            float4 wv[4][2];
#pragma unroll
            for (int r = 0; r < 8; ++r)
                xv[r] = *reinterpret_cast<const float4*>(&xs[(ry + r) * 64 + kq * 4]);
#pragma unroll
            for (int k2 = 0; k2 < 4; ++k2) {
                wv[k2][0] = *reinterpret_cast<const float4*>(&ws[(kq * 4 + k2) * 128 + cx]);
                wv[k2][1] = *reinterpret_cast<const float4*>(&ws[(kq * 4 + k2) * 128 + cx + 4]);
            }
#pragma unroll
            for (int r = 0; r < 8; ++r) {
                const float* xf = reinterpret_cast<const float*>(&xv[r]);
#pragma unroll
                for (int k2 = 0; k2 < 4; ++k2) {
                    const float xx = xf[k2];
                    const float* w0 = reinterpret_cast<const float*>(&wv[k2][0]);
                    const float* w1 = reinterpret_cast<const float*>(&wv[k2][1]);
#pragma unroll
                    for (int c = 0; c < 4; ++c) {
                        acc[r][c] = fmaf(xx, w0[c], acc[r][c]);
                        acc[r][c + 4] = fmaf(xx, w1[c], acc[r][c + 4]);
                    }
                }
            }
        }
    }
#pragma unroll
    for (int r = 0; r < 8; ++r) {
        int gr = nbase + ry + r;
        if (gr < N_NODES) {
            *reinterpret_cast<float4*>(&h[(size_t)gr * 128 + cx]) =
                make_float4(acc[r][0], acc[r][1], acc[r][2], acc[r][3]);
            *reinterpret_cast<float4*>(&h[(size_t)gr * 128 + cx + 4]) =
                make_float4(acc[r][4], acc[r][5], acc[r][6], acc[r][7]);
        }
    }

    // ---- fused a_src epilogue: reuse xs as [128 rows][16 col-group slots] ----
    float asv[8];
#pragma unroll
    for (int c = 0; c < 8; ++c) asv[c] = att_src[cx + c];
    __syncthreads();   // everyone done reading xs/ws in the main loop
#pragma unroll
    for (int r = 0; r < 8; ++r) {
        float p = 0.f;
#pragma unroll
        for (int c = 0; c < 8; ++c) p += acc[r][c] * asv[c];
        xs[(ry + r) * 16 + (t & 15)] = p;
    }
    __syncthreads();
    // pair-reduce the two 8-col slots of each head; 1024 (row,head) entries
    for (int idx = t; idx < 1024; idx += 256) {
        int row = idx >> 3, hd = idx & 7;
        int gr = nbase + row;
        if (gr < N_NODES)
            a_srcp[gr * 8 + hd] = xs[row * 16 + hd * 2] + xs[row * 16 + hd * 2 + 1];
    }
}

// ---------------- degree count ----------------
__global__ __launch_bounds__(256) void deg_kernel(const int* __restrict__ ei, int* __restrict__ deg) {
    int i = blockIdx.x * 256 + threadIdx.x;
    if (i < N_EDGES) atomicAdd(&deg[ei[N_EDGES + i]], 1);
}

// ---------------- exclusive scan (3 kernels) ----------------
__global__ __launch_bounds__(256) void scan1_kernel(const int* __restrict__ deg,
                                                    int* __restrict__ rowptr,
                                                    int* __restrict__ blocksum) {
    __shared__ int sdata[256];
    const int t = threadIdx.x;
    const int gbase = blockIdx.x * 1024 + t * 4;
    int v[4];
#pragma unroll
    for (int j = 0; j < 4; ++j) v[j] = (gbase + j < N_NODES) ? deg[gbase + j] : 0;
    int tot = v[0] + v[1] + v[2] + v[3];
    sdata[t] = tot;
    __syncthreads();
    for (int off = 1; off < 256; off <<= 1) {
        int u = (t >= off) ? sdata[t - off] : 0;
        __syncthreads();
        sdata[t] += u;
        __syncthreads();
    }
    int excl = sdata[t] - tot;
    int run = excl;
#pragma unroll
    for (int j = 0; j < 4; ++j) {
        if (gbase + j < N_NODES) rowptr[gbase + j] = run;
        run += v[j];
    }
    if (t == 255) blocksum[blockIdx.x] = sdata[255];
}

__global__ __launch_bounds__(128) void scan2_kernel(int* __restrict__ blocksum, int nblocks) {
    __shared__ int sdata[128];
    const int t = threadIdx.x;
    int v = (t < nblocks) ? blocksum[t] : 0;
    sdata[t] = v;
    __syncthreads();
    for (int off = 1; off < 128; off <<= 1) {
        int u = (t >= off) ? sdata[t - off] : 0;
        __syncthreads();
        sdata[t] += u;
        __syncthreads();
    }
    if (t < nblocks) blocksum[t] = sdata[t] - v;   // exclusive
}

__global__ __launch_bounds__(256) void scan3_kernel(int* __restrict__ rowptr,
                                                    int* __restrict__ cursor,
                                                    const int* __restrict__ blocksum) {
    const int t = threadIdx.x;
    const int gbase = blockIdx.x * 1024 + t * 4;
    int off = blocksum[blockIdx.x];
#pragma unroll
    for (int j = 0; j < 4; ++j) {
        int i = gbase + j;
        if (i < N_NODES) {
            int val = rowptr[i] + off;
            rowptr[i] = val;
            cursor[i] = val;
        }
    }
    if (blockIdx.x == 0 && t == 0) rowptr[N_NODES] = N_EDGES;
}

// ---------------- scatter edges into CSR ----------------
__global__ __launch_bounds__(256) void scatter_kernel(const int* __restrict__ ei,
                                                      int* __restrict__ cursor,
                                                      int* __restrict__ csr_src) {
    int i = blockIdx.x * 256 + threadIdx.x;
    if (i >= N_EDGES) return;
    int src = ei[i];
    int dst = ei[N_EDGES + i];
    int pos = atomicAdd(&cursor[dst], 1);
    csr_src[pos] = src;
}

// ---------------- fused per-node aggregate + softmax + LN ----------------
// one 64-lane wave per node, split into two 32-lane halves.
// half = lane>>5 processes edges beg+half, beg+half+2, ...
// lane-within-half hl owns channels 4*hl .. 4*hl+3 (float4 gathers); head = hl>>2
__global__ __launch_bounds__(256) void node_aggregate_kernel(const int* __restrict__ rowptr,
                                                             const int* __restrict__ csr_src,
                                                             const float* __restrict__ h,
                                                             const float* __restrict__ a_srcp,
                                                             const float* __restrict__ x,
                                                             const float* __restrict__ att_dst,
                                                             const float* __restrict__ bias,
                                                             const float* __restrict__ gamma,
                                                             const float* __restrict__ beta,
                                                             float* __restrict__ out) {
    int node = blockIdx.x * 4 + (threadIdx.x >> 6);
    if (node >= N_NODES) return;
    const int lane = threadIdx.x & 63;
    const int half = lane >> 5;        // which 32-lane half
    const int hl = lane & 31;          // lane within half
    const int ch = hl * 4;             // 4 channels per lane
    const int head = hl >> 2;          // 4 lanes per head

    // a_dst for this node's head: 4-lane-group reduce (prologue only)
    float4 adv = *reinterpret_cast<const float4*>(att_dst + ch);
    float4 hn = *reinterpret_cast<const float4*>(h + (size_t)node * 128 + ch);
    float pd = hn.x * adv.x + hn.y * adv.y + hn.z * adv.z + hn.w * adv.w;
    pd += __shfl_xor(pd, 1);
    pd += __shfl_xor(pd, 2);
    const float adst = pd;

    const int beg = rowptr[node];
    const int end = rowptr[node + 1];

    float s = 0.f, acc0 = 0.f, acc1 = 0.f, acc2 = 0.f, acc3 = 0.f;

    const float4* __restrict__ hp = reinterpret_cast<const float4*>(h);

    int i = beg + half;
    if (i < end) {
        const int sA = csr_src[i];
        int sB = (i + 2 < end) ? csr_src[i + 2] : sA;
        float4 hv = hp[sA * 32 + hl];
        float as = a_srcp[sA * 8 + head];
        while (true) {
            const float4 hc = hv;
            const float ac = as;
            const int sN = sB;
            const int i4 = i + 4;
            sB = (i4 < end) ? csr_src[i4] : sA;     // index 2 iterations ahead
            hv = hp[sN * 32 + hl];                   // gather 1 iteration ahead
            as = a_srcp[sN * 8 + head];
            float e = ac + adst;
            e = e >= 0.f ? e : NEG_SLOPE * e;
            e = fminf(e, 80.f);                      // overflow insurance (no-op here)
            const float p = __expf(e);
            s += p;
            acc0 = fmaf(p, hc.x, acc0);
            acc1 = fmaf(p, hc.y, acc1);
            acc2 = fmaf(p, hc.z, acc2);
            acc3 = fmaf(p, hc.w, acc3);
            i += 2;
            if (i >= end) break;
        }
    }

    // combine the two halves (each channel now duplicated across halves)
    s += __shfl_xor(s, 32);
    acc0 += __shfl_xor(acc0, 32);
    acc1 += __shfl_xor(acc1, 32);
    acc2 += __shfl_xor(acc2, 32);
    acc3 += __shfl_xor(acc3, 32);

    // normalize + bias + residual
    const float rs = 1.0f / (s + 1e-16f);
    float4 xr = *reinterpret_cast<const float4*>(x + (size_t)node * 128 + ch);
    float4 bv = *reinterpret_cast<const float4*>(bias + ch);
    float v0 = acc0 * rs + bv.x + xr.x;
    float v1 = acc1 * rs + bv.y + xr.y;
    float v2 = acc2 * rs + bv.z + xr.z;
    float v3 = acc3 * rs + bv.w + xr.w;

    // LayerNorm over 128 channels (full-wave reduce; every channel counted twice)
    float sum = v0 + v1 + v2 + v3;
    float sq = v0 * v0 + v1 * v1 + v2 * v2 + v3 * v3;
#pragma unroll
    for (int off = 32; off > 0; off >>= 1) {
        sum += __shfl_xor(sum, off);
        sq += __shfl_xor(sq, off);
    }
    const float mu = sum * (1.0f / 256.0f);
    const float var = sq * (1.0f / 256.0f) - mu * mu;
    const float inv = rsqrtf(var + LN_EPS);
    float4 gv = *reinterpret_cast<const float4*>(gamma + ch);
    float4 be = *reinterpret_cast<const float4*>(beta + ch);
    float o0 = (v0 - mu) * inv * gv.x + be.x;
    float o1 = (v1 - mu) * inv * gv.y + be.y;
    float o2 = (v2 - mu) * inv * gv.z + be.z;
    float o3 = (v3 - mu) * inv * gv.w + be.w;
    o0 = o0 > 0.f ? o0 : 0.f;
    o1 = o1 > 0.f ? o1 : 0.f;
    o2 = o2 > 0.f ? o2 : 0.f;
    o3 = o3 > 0.f ? o3 : 0.f;
    if (half == 0) {
        *reinterpret_cast<float4*>(out + (size_t)node * 128 + ch) = make_float4(o0, o1, o2, o3);
    }
}

extern "C" void kernel_launch(void* const* d_in, const int* in_sizes, int n_in,
                              void* d_out, int out_size, void* d_ws, size_t ws_size,
                              hipStream_t stream) {
    const float* x = (const float*)d_in[0];
    const int* ei = (const int*)d_in[1];
    const float* W = (const float*)d_in[2];
    const float* att_src = (const float*)d_in[3];
    const float* att_dst = (const float*)d_in[4];
    const float* bias = (const float*)d_in[5];
    const float* gamma = (const float*)d_in[6];
    const float* beta = (const float*)d_in[7];
    float* out = (float*)d_out;

    char* base = (char*)d_ws;
    float* h      = (float*)base;                       // 51.2 MB
    float* a_srcp = (float*)(base + 51200000);          // 3.2 MB
    int* csr_src  = (int*)(base + 54400000);            // 6.4 MB
    int* rowptr   = (int*)(base + 60800000);            // 400,004 B
    int* cursor   = (int*)(base + 61200128);            // 400,004 B (also deg)
    int* blocksum = (int*)(base + 61600256);            // 512 B

    const int nscan = (N_NODES + 1023) / 1024;          // 98

    hipMemsetAsync(cursor, 0, (N_NODES) * sizeof(int), stream);   // deg = 0
    gemm_kernel<<<(N_NODES + 127) / 128, 256, 0, stream>>>(x, W, att_src, h, a_srcp);
    deg_kernel<<<(N_EDGES + 255) / 256, 256, 0, stream>>>(ei, cursor);
    scan1_kernel<<<nscan, 256, 0, stream>>>(cursor, rowptr, blocksum);
    scan2_kernel<<<1, 128, 0, stream>>>(blocksum, nscan);
    scan3_kernel<<<nscan, 256, 0, stream>>>(rowptr, cursor, blocksum);
    scatter_kernel<<<(N_EDGES + 255) / 256, 256, 0, stream>>>(ei, cursor, csr_src);
    node_aggregate_kernel<<<(N_NODES + 3) / 4, 256, 0, stream>>>(
        rowptr, csr_src, h, a_srcp, x, att_dst, bias, gamma, beta, out);
}